// Round 3
// baseline (2474.955 us; speedup 1.0000x reference)
//
#include <hip/hip_runtime.h>

// LemInFrameMoE on MI355X (gfx950).
// N=32768 nodes, E=131072 edges, D=128, K_onehot=64, NEXP=8, HID=128.
// Output = [node (N*128) | edge_messages (E*128)] f32.
//
// Precision scheme: all GEMM operands that come from activations are split
// hi/lo bf16 (v = hi + lo exactly to ~2^-17 rel), each GEMM runs two MFMA
// passes into one f32 accumulator -> effectively f32-precision operands.
// Weights stay single bf16 (rel 2e-3, negligible at threshold 2%).
//
// R3 fix vs R2: env-GEMM lat staging covered only 32 of 64 floats per
// half-row (stale msg_lo in cols 32-63/96-127 -> env half-wrong -> node
// error 1.73). Now stages the full 64 floats via 16x float4.

#define NND 32768
#define NED 131072
#define DIM 128
#define KOH 64

typedef unsigned short u16;
typedef short bf16x8 __attribute__((ext_vector_type(8)));
typedef float f32x4 __attribute__((ext_vector_type(4)));

#define MFMA16 __builtin_amdgcn_mfma_f32_16x16x32_bf16

__device__ __forceinline__ u16 f2b(float f){
  unsigned u = __builtin_bit_cast(unsigned, f);
  u += 0x7fffu + ((u >> 16) & 1u);
  return (u16)(u >> 16);
}
__device__ __forceinline__ float b2f(u16 h){
  return __builtin_bit_cast(float, ((unsigned)h) << 16);
}

// ---------------- K0: weight prep (cast/transpose to bf16) ----------------
__global__ __launch_bounds__(256) void k_prep(
    const float* __restrict__ W_moe, const float* __restrict__ W_post,
    const float* __restrict__ W_env, const float* __restrict__ w_oh,
    u16* __restrict__ wmoeT, u16* __restrict__ wpostT, u16* __restrict__ wenvT,
    u16* __restrict__ wohb){
  const int t = blockIdx.x * 256 + threadIdx.x;
  if (t < 8*DIM*384){                       // wmoeT[n][h][d] = W_moe[n][d][h]
    const int d = t % 384, h = (t/384) % DIM, n = t/(384*DIM);
    wmoeT[t] = f2b(W_moe[(n*384 + d)*DIM + h]);
  }
  if (t < DIM*DIM){                         // [out][in] = W[in][out]
    const int a = t % DIM, b = t / DIM;
    wpostT[t] = f2b(W_post[a*DIM + b]);
    wenvT[t]  = f2b(W_env [a*DIM + b]);
  }
  if (t < DIM*KOH) wohb[t] = f2b(w_oh[t]); // w_oh already [D][K]
}

// ---------------- K1: node LayerNorm -> hi/lo bf16 ----------------
__global__ __launch_bounds__(256) void k_node_ln(
    const float* __restrict__ nf, const float* __restrict__ gamma,
    const float* __restrict__ beta, u16* __restrict__ nn_hi,
    u16* __restrict__ nn_lo){
  const int node = (blockIdx.x*256 + threadIdx.x) >> 6;
  const int lane = threadIdx.x & 63;
  if (node >= NND) return;
  const float2 v = *(const float2*)(nf + (size_t)node*DIM + lane*2);
  float s = v.x + v.y, sq = v.x*v.x + v.y*v.y;
  #pragma unroll
  for (int o=1;o<64;o<<=1){ s += __shfl_xor(s,o); sq += __shfl_xor(sq,o); }
  const float mu = s * (1.f/128.f);
  const float var = sq * (1.f/128.f) - mu*mu;
  const float rs = 1.f / sqrtf(var + 1e-8f);
  const float2 g = *(const float2*)(gamma + lane*2);
  const float2 b = *(const float2*)(beta  + lane*2);
  const float f0 = (v.x-mu)*rs*g.x + b.x;
  const float f1 = (v.y-mu)*rs*g.y + b.y;
  const u16 h0 = f2b(f0), h1 = f2b(f1);
  const u16 l0 = f2b(f0 - b2f(h0)), l1 = f2b(f1 - b2f(h1));
  *(unsigned*)(nn_hi + (size_t)node*DIM + lane*2) = (unsigned)h0 | ((unsigned)h1 << 16);
  *(unsigned*)(nn_lo + (size_t)node*DIM + lane*2) = (unsigned)l0 | ((unsigned)l1 << 16);
}

// ---------------- K2: per-edge router softmax + edge-LN stats ----------------
__global__ __launch_bounds__(256) void k_edge_prep(
    const float* __restrict__ latents, const float* __restrict__ ef,
    const int* __restrict__ active_edges, const float* __restrict__ W_router,
    float* __restrict__ gate, float* __restrict__ eln){
  const int e = (blockIdx.x*256 + threadIdx.x) >> 6;
  const int lane = threadIdx.x & 63;
  if (e >= NED) return;
  const int a = active_edges[e];
  const float2 lv = *(const float2*)(latents + (size_t)a*DIM + lane*2);
  float p[8];
  {
    const float4 wa0 = *(const float4*)(W_router + (lane*2)*8);
    const float4 wa1 = *(const float4*)(W_router + (lane*2)*8 + 4);
    const float4 wb0 = *(const float4*)(W_router + (lane*2+1)*8);
    const float4 wb1 = *(const float4*)(W_router + (lane*2+1)*8 + 4);
    p[0] = lv.x*wa0.x + lv.y*wb0.x;  p[1] = lv.x*wa0.y + lv.y*wb0.y;
    p[2] = lv.x*wa0.z + lv.y*wb0.z;  p[3] = lv.x*wa0.w + lv.y*wb0.w;
    p[4] = lv.x*wa1.x + lv.y*wb1.x;  p[5] = lv.x*wa1.y + lv.y*wb1.y;
    p[6] = lv.x*wa1.z + lv.y*wb1.z;  p[7] = lv.x*wa1.w + lv.y*wb1.w;
  }
  #pragma unroll
  for (int o=1;o<64;o<<=1){
    #pragma unroll
    for (int i=0;i<8;i++) p[i] += __shfl_xor(p[i], o);
  }
  float m = p[0];
  #pragma unroll
  for (int i=1;i<8;i++) m = fmaxf(m, p[i]);
  float ex[8], sum = 0.f;
  #pragma unroll
  for (int i=0;i<8;i++){ ex[i] = __expf(p[i]-m); sum += ex[i]; }
  const float inv = 1.f / sum;
  if (lane < 8) gate[(size_t)e*8 + lane] = ex[lane]*inv;

  const float2 fv = *(const float2*)(ef + (size_t)a*DIM + lane*2);
  float s = fv.x + fv.y, sq = fv.x*fv.x + fv.y*fv.y;
  #pragma unroll
  for (int o=1;o<64;o<<=1){ s += __shfl_xor(s,o); sq += __shfl_xor(sq,o); }
  if (lane == 0){
    const float mu = s * (1.f/128.f);
    const float var = sq * (1.f/128.f) - mu*mu;
    eln[(size_t)e*2]   = mu;
    eln[(size_t)e*2+1] = 1.f / sqrtf(var + 1e-8f);
  }
}

// ---------------- K3: fused edge MoE (hot kernel) ----------------
// 128 edges/block, 4 waves (2x2 over h x edge). All activation GEMM operands
// are hi/lo split. region reuse timeline:
//   [0,25600)      x-tile [128][200]          (staged 4x: 2 halves x hi/lo)
//   [0,17408)      msg_hi [128][136]          (after MoE)
//   [17408,34816)  msg_lo [128][136]
//   [17408,34816)  lat bf16 [128][136]        (after post-GEMM, for env)
__global__ __launch_bounds__(256, 2) void k_edge_moe(
    const u16* __restrict__ nn_hi, const u16* __restrict__ nn_lo,
    const float* __restrict__ edge_features, const float* __restrict__ latents,
    const int* __restrict__ edge_index, const int* __restrict__ active_edges,
    const float* __restrict__ gamma_e, const float* __restrict__ beta_e,
    const float* __restrict__ gate, const float* __restrict__ eln,
    const u16* __restrict__ wmoeT, const float* __restrict__ b_moe,
    const u16* __restrict__ wpostT, const float* __restrict__ b_post,
    const u16* __restrict__ wenvT, const float* __restrict__ b_env,
    float* __restrict__ agg, float* __restrict__ out_em){
  __shared__ __align__(16) u16 region[34816];
  __shared__ __align__(16) float gate_f[128*8];
  __shared__ int ecs[128]; __shared__ int ens[128]; __shared__ int aes[128];

  const int tid  = threadIdx.x;
  const int lane = tid & 63;
  const int w    = tid >> 6;
  const int wm   = w >> 1, wn = w & 1;
  const int e0   = blockIdx.x * 128;

  if (tid < 128){
    const int a = active_edges[e0 + tid];
    aes[tid] = a;
    ecs[tid] = edge_index[a];
    ens[tid] = edge_index[NED + a];
  }
  *(float4*)(&gate_f[tid*4]) = *(const float4*)(gate + (size_t)e0*8 + tid*4);
  __syncthreads();

  // gate scalars: gsc[n][ni] = gate[e_col(ni)][n]
  float gsc[8][4];
  #pragma unroll
  for (int ni=0;ni<4;ni++){
    const int ecol = wn*64 + ni*16 + (lane & 15);
    #pragma unroll
    for (int n=0;n<8;n++) gsc[n][ni] = gate_f[ecol*8 + n];
  }

  const f32x4 z4 = {0.f,0.f,0.f,0.f};
  f32x4 msgacc[4][4];
  #pragma unroll
  for (int mi=0;mi<4;mi++)
    #pragma unroll
    for (int ni=0;ni<4;ni++) msgacc[mi][ni] = z4;

  const int r  = tid >> 1, hf = tid & 1;      // staging row / half-row
  const float mu = eln[(size_t)(e0+r)*2], rsld = eln[(size_t)(e0+r)*2+1];

  #pragma unroll
  for (int half=0; half<2; half++){
    const int h0 = half * 192;
    #pragma unroll
    for (int part=0; part<2; part++){
      __syncthreads();
      { // stage x part: 6 k-chunks of 32, 16 elems per (thread,chunk)
        const u16* nsrc = part ? nn_lo : nn_hi;
        const int ia = aes[r], ic = ecs[r], inb = ens[r];
        #pragma unroll
        for (int c=0;c<6;c++){
          const int kg = h0 + c*32 + hf*16;
          u16* dst = &region[r*200 + c*32 + hf*16];
          if (kg < 128){                              // nn[ec]
            const uint4* s4 = (const uint4*)(nsrc + (size_t)ic*DIM + kg);
            ((uint4*)dst)[0] = s4[0]; ((uint4*)dst)[1] = s4[1];
          } else if (kg < 256){                       // LN(edge_features) on the fly
            const int kk = kg - 128;
            const float* src = edge_features + (size_t)ia*DIM + kk;
            #pragma unroll
            for (int q=0;q<4;q++){
              const float4 v  = *(const float4*)(src + q*4);
              const float4 g4 = *(const float4*)(gamma_e + kk + q*4);
              const float4 b4 = *(const float4*)(beta_e  + kk + q*4);
              float f0=(v.x-mu)*rsld*g4.x+b4.x, f1=(v.y-mu)*rsld*g4.y+b4.y;
              float f2=(v.z-mu)*rsld*g4.z+b4.z, f3=(v.w-mu)*rsld*g4.w+b4.w;
              u16 o0,o1,o2,o3;
              if (part == 0){ o0=f2b(f0); o1=f2b(f1); o2=f2b(f2); o3=f2b(f3); }
              else {
                o0=f2b(f0 - b2f(f2b(f0))); o1=f2b(f1 - b2f(f2b(f1)));
                o2=f2b(f2 - b2f(f2b(f2))); o3=f2b(f3 - b2f(f2b(f3)));
              }
              ((unsigned*)dst)[q*2]   = (unsigned)o0 | ((unsigned)o1<<16);
              ((unsigned*)dst)[q*2+1] = (unsigned)o2 | ((unsigned)o3<<16);
            }
          } else {                                    // nn[en]
            const uint4* s4 = (const uint4*)(nsrc + (size_t)inb*DIM + (kg-256));
            ((uint4*)dst)[0] = s4[0]; ((uint4*)dst)[1] = s4[1];
          }
        }
      }
      __syncthreads();

      #pragma unroll
      for (int n=0;n<8;n++){
        const u16* wA = wmoeT + (size_t)n*(DIM*384);
        f32x4 cacc[4][4];
        #pragma unroll
        for (int kk=0;kk<6;kk++){
          bf16x8 a[4], b[4];
          #pragma unroll
          for (int mi=0;mi<4;mi++)
            a[mi] = *(const bf16x8*)(wA + (wm*64 + mi*16 + (lane&15))*384 + h0 + kk*32 + ((lane>>4)*8));
          #pragma unroll
          for (int ni=0;ni<4;ni++)
            b[ni] = *(const bf16x8*)(&region[(wn*64 + ni*16 + (lane&15))*200 + kk*32 + ((lane>>4)*8)]);
          #pragma unroll
          for (int mi=0;mi<4;mi++)
            #pragma unroll
            for (int ni=0;ni<4;ni++)
              cacc[mi][ni] = MFMA16(a[mi], b[ni], (kk==0) ? z4 : cacc[mi][ni], 0,0,0);
        }
        #pragma unroll
        for (int mi=0;mi<4;mi++)
          #pragma unroll
          for (int ni=0;ni<4;ni++)
            msgacc[mi][ni] += gsc[n][ni] * cacc[mi][ni];
      }
    }
  }

  // exact f32 bias epilogue: msg[h][e] += sum_n gate[e][n]*b_moe[n][h]
  #pragma unroll
  for (int mi=0;mi<4;mi++){
    const int d0 = wm*64 + mi*16 + ((lane>>4)<<2);
    float bsum[4][4]; // [reg][ni]
    #pragma unroll
    for (int reg=0;reg<4;reg++)
      #pragma unroll
      for (int ni=0;ni<4;ni++) bsum[reg][ni] = 0.f;
    #pragma unroll
    for (int n=0;n<8;n++){
      const float4 bm = *(const float4*)(b_moe + n*DIM + d0);
      #pragma unroll
      for (int ni=0;ni<4;ni++){
        bsum[0][ni] += gsc[n][ni]*bm.x; bsum[1][ni] += gsc[n][ni]*bm.y;
        bsum[2][ni] += gsc[n][ni]*bm.z; bsum[3][ni] += gsc[n][ni]*bm.w;
      }
    }
    #pragma unroll
    for (int ni=0;ni<4;ni++)
      #pragma unroll
      for (int reg=0;reg<4;reg++) msgacc[mi][ni][reg] += bsum[reg][ni];
  }

  __syncthreads();   // all x-tile reads done before region reuse
  u16* msg_hi = region;
  u16* msg_lo = region + 17408;
  #pragma unroll
  for (int mi=0;mi<4;mi++){
    const int hb = wm*64 + mi*16 + ((lane>>4)<<2);
    #pragma unroll
    for (int ni=0;ni<4;ni++){
      const int el = wn*64 + ni*16 + (lane & 15);
      const f32x4 v = msgacc[mi][ni];
      float sl[4];
      #pragma unroll
      for (int j=0;j<4;j++){ const float s=v[j]; sl[j] = s / (1.f + __expf(-s)); }
      u16 h[4], l[4];
      #pragma unroll
      for (int j=0;j<4;j++){ h[j] = f2b(sl[j]); l[j] = f2b(sl[j] - b2f(h[j])); }
      *(uint2*)(&msg_hi[el*136 + hb]) =
        make_uint2((unsigned)h[0] | ((unsigned)h[1]<<16), (unsigned)h[2] | ((unsigned)h[3]<<16));
      *(uint2*)(&msg_lo[el*136 + hb]) =
        make_uint2((unsigned)l[0] | ((unsigned)l[1]<<16), (unsigned)l[2] | ((unsigned)l[3]<<16));
    }
  }
  __syncthreads();

  // post-GEMM: em^T = W_postT @ (silu_hi + silu_lo)^T
  f32x4 em[4][4];
  #pragma unroll
  for (int kk=0;kk<4;kk++){
    bf16x8 a[4], bh[4], bl[4];
    #pragma unroll
    for (int mi=0;mi<4;mi++)
      a[mi] = *(const bf16x8*)(wpostT + (wm*64 + mi*16 + (lane&15))*DIM + kk*32 + ((lane>>4)*8));
    #pragma unroll
    for (int ni=0;ni<4;ni++){
      const int el = wn*64 + ni*16 + (lane&15);
      bh[ni] = *(const bf16x8*)(&msg_hi[el*136 + kk*32 + ((lane>>4)*8)]);
      bl[ni] = *(const bf16x8*)(&msg_lo[el*136 + kk*32 + ((lane>>4)*8)]);
    }
    #pragma unroll
    for (int mi=0;mi<4;mi++)
      #pragma unroll
      for (int ni=0;ni<4;ni++){
        em[mi][ni] = MFMA16(a[mi], bh[ni], (kk==0) ? z4 : em[mi][ni], 0,0,0);
        em[mi][ni] = MFMA16(a[mi], bl[ni], em[mi][ni], 0,0,0);
      }
  }
  // + b_post, write edge_messages
  #pragma unroll
  for (int mi=0;mi<4;mi++){
    const int d0 = wm*64 + mi*16 + ((lane>>4)<<2);
    const float4 bp = *(const float4*)(b_post + d0);
    #pragma unroll
    for (int ni=0;ni<4;ni++){
      const int el = wn*64 + ni*16 + (lane & 15);
      em[mi][ni][0] += bp.x; em[mi][ni][1] += bp.y;
      em[mi][ni][2] += bp.z; em[mi][ni][3] += bp.w;
      float4 o; o.x = em[mi][ni][0]; o.y = em[mi][ni][1];
      o.z = em[mi][ni][2]; o.w = em[mi][ni][3];
      *(float4*)(out_em + (size_t)(e0+el)*DIM + d0) = o;
    }
  }

  // env-GEMM: env^T = W_envT @ lat^T (lat bf16 tile in dead msg_lo area)
  __syncthreads();   // all msg reads done
  u16* lbuf = region + 17408;
  {
    // R3 FIX: stage ALL 64 floats of this half-row (was 32 -> stale cols).
    const float* src = latents + (size_t)aes[r]*DIM + hf*64;
    u16* dst = lbuf + r*136 + hf*64;
    #pragma unroll
    for (int q=0;q<16;q++){
      const float4 v = *(const float4*)(src + q*4);
      ((unsigned*)dst)[q*2]   = (unsigned)f2b(v.x) | ((unsigned)f2b(v.y)<<16);
      ((unsigned*)dst)[q*2+1] = (unsigned)f2b(v.z) | ((unsigned)f2b(v.w)<<16);
    }
  }
  __syncthreads();
  f32x4 env[4][4];
  #pragma unroll
  for (int kk=0;kk<4;kk++){
    bf16x8 a[4], b[4];
    #pragma unroll
    for (int mi=0;mi<4;mi++)
      a[mi] = *(const bf16x8*)(wenvT + (wm*64 + mi*16 + (lane&15))*DIM + kk*32 + ((lane>>4)*8));
    #pragma unroll
    for (int ni=0;ni<4;ni++)
      b[ni] = *(const bf16x8*)(&lbuf[(wn*64 + ni*16 + (lane&15))*136 + kk*32 + ((lane>>4)*8)]);
    #pragma unroll
    for (int mi=0;mi<4;mi++)
      #pragma unroll
      for (int ni=0;ni<4;ni++)
        env[mi][ni] = MFMA16(a[mi], b[ni], (kk==0) ? z4 : env[mi][ni], 0,0,0);
  }

  // msg_w = em * (env + b_env); atomic scatter to agg[ec]
  #pragma unroll
  for (int mi=0;mi<4;mi++){
    const int d0 = wm*64 + mi*16 + ((lane>>4)<<2);
    const float4 be = *(const float4*)(b_env + d0);
    #pragma unroll
    for (int ni=0;ni<4;ni++){
      const int el = wn*64 + ni*16 + (lane & 15);
      const int node = ecs[el];
      float* ag = agg + (size_t)node*DIM + d0;
      atomicAdd(ag+0, em[mi][ni][0] * (env[mi][ni][0] + be.x));
      atomicAdd(ag+1, em[mi][ni][1] * (env[mi][ni][1] + be.y));
      atomicAdd(ag+2, em[mi][ni][2] * (env[mi][ni][2] + be.z));
      atomicAdd(ag+3, em[mi][ni][3] * (env[mi][ni][3] + be.w));
    }
  }
}

// ---------------- K4: node residual + onehot elementwise TP ----------------
__global__ __launch_bounds__(256, 2) void k_node_out(
    const float* __restrict__ nf, const float* __restrict__ onehot,
    const u16* __restrict__ wohb, const float* __restrict__ agg,
    float* __restrict__ out_node){
  __shared__ __align__(16) u16 oh[128*72];
  const int tid = threadIdx.x, lane = tid & 63, w = tid >> 6;
  const int wm = w >> 1, wn = w & 1;
  const int n0 = blockIdx.x * 128;
  {
    const int r = tid >> 1, hf = tid & 1;
    const float* src = onehot + (size_t)(n0+r)*KOH + hf*32;
    u16* dst = &oh[r*72 + hf*32];
    #pragma unroll
    for (int q=0;q<8;q++){
      const float4 v = *(const float4*)(src + q*4);
      ((unsigned*)dst)[q*2]   = (unsigned)f2b(v.x) | ((unsigned)f2b(v.y)<<16);
      ((unsigned*)dst)[q*2+1] = (unsigned)f2b(v.z) | ((unsigned)f2b(v.w)<<16);
    }
  }
  __syncthreads();
  const f32x4 z4 = {0.f,0.f,0.f,0.f};
  f32x4 sacc[4][4];
  #pragma unroll
  for (int kk=0;kk<2;kk++){
    bf16x8 a[4], b[4];
    #pragma unroll
    for (int mi=0;mi<4;mi++)
      a[mi] = *(const bf16x8*)(wohb + (wm*64 + mi*16 + (lane&15))*KOH + kk*32 + ((lane>>4)*8));
    #pragma unroll
    for (int ni=0;ni<4;ni++)
      b[ni] = *(const bf16x8*)(&oh[(wn*64 + ni*16 + (lane&15))*72 + kk*32 + ((lane>>4)*8)]);
    #pragma unroll
    for (int mi=0;mi<4;mi++)
      #pragma unroll
      for (int ni=0;ni<4;ni++)
        sacc[mi][ni] = MFMA16(a[mi], b[ni], (kk==0) ? z4 : sacc[mi][ni], 0,0,0);
  }
  const float c_old = 0.8944271909999159f;        // 1/sqrt(1.25)
  const float c_new = 0.4472135954999579f * 0.5f; // u*c_old * rsqrt(4)
  #pragma unroll
  for (int ni=0;ni<4;ni++){
    const int node = n0 + wn*64 + ni*16 + (lane & 15);
    #pragma unroll
    for (int mi=0;mi<4;mi++){
      const int d0 = wm*64 + mi*16 + ((lane>>4)<<2);
      const float4 nv = *(const float4*)(nf  + (size_t)node*DIM + d0);
      const float4 av = *(const float4*)(agg + (size_t)node*DIM + d0);
      float4 o;
      o.x = (c_old*nv.x + c_new*av.x) * (1.f + sacc[mi][ni][0]);
      o.y = (c_old*nv.y + c_new*av.y) * (1.f + sacc[mi][ni][1]);
      o.z = (c_old*nv.z + c_new*av.z) * (1.f + sacc[mi][ni][2]);
      o.w = (c_old*nv.w + c_new*av.w) * (1.f + sacc[mi][ni][3]);
      *(float4*)(out_node + (size_t)node*DIM + d0) = o;
    }
  }
}

// ---------------- launch ----------------
extern "C" void kernel_launch(void* const* d_in, const int* in_sizes, int n_in,
                              void* d_out, int out_size, void* d_ws, size_t ws_size,
                              hipStream_t stream){
  const float* latents       = (const float*)d_in[0];
  const float* node_features = (const float*)d_in[1];
  const float* edge_features = (const float*)d_in[2];
  const float* node_onehot   = (const float*)d_in[3];
  const int*   edge_index    = (const int*)d_in[6];
  const int*   active_edges  = (const int*)d_in[7];
  const float* gamma_n       = (const float*)d_in[8];
  const float* beta_n        = (const float*)d_in[9];
  const float* gamma_e       = (const float*)d_in[10];
  const float* beta_e        = (const float*)d_in[11];
  const float* W_router      = (const float*)d_in[12];
  const float* W_moe         = (const float*)d_in[13];
  const float* b_moe         = (const float*)d_in[14];
  const float* W_post        = (const float*)d_in[15];
  const float* b_post        = (const float*)d_in[16];
  const float* W_env         = (const float*)d_in[17];
  const float* b_env         = (const float*)d_in[18];
  const float* w_oh          = (const float*)d_in[19];

  char* ws = (char*)d_ws;
  u16*   nn_hi  = (u16*)  (ws + 0);
  u16*   nn_lo  = (u16*)  (ws + 8388608);
  float* gate   = (float*)(ws + 16777216);
  float* eln    = (float*)(ws + 20971520);
  float* agg    = (float*)(ws + 22020096);
  u16*   wmoeT  = (u16*)  (ws + 38797312);
  u16*   wpostT = (u16*)  (ws + 39583744);
  u16*   wenvT  = (u16*)  (ws + 39616512);
  u16*   wohb   = (u16*)  (ws + 39649280);

  float* out_node = (float*)d_out;
  float* out_em   = out_node + (size_t)NND*DIM;

  hipMemsetAsync(agg, 0, (size_t)NND*DIM*sizeof(float), stream);
  k_prep<<<1536, 256, 0, stream>>>(W_moe, W_post, W_env, w_oh,
                                   wmoeT, wpostT, wenvT, wohb);
  k_node_ln<<<8192, 256, 0, stream>>>(node_features, gamma_n, beta_n, nn_hi, nn_lo);
  k_edge_prep<<<32768, 256, 0, stream>>>(latents, edge_features, active_edges,
                                         W_router, gate, eln);
  k_edge_moe<<<1024, 256, 0, stream>>>(nn_hi, nn_lo, edge_features, latents,
                                       edge_index, active_edges,
                                       gamma_e, beta_e, gate, eln,
                                       wmoeT, b_moe, wpostT, b_post,
                                       wenvT, b_env, agg, out_em);
  k_node_out<<<256, 256, 0, stream>>>(node_features, node_onehot, wohb, agg, out_node);
}